// Round 3
// baseline (539.255 us; speedup 1.0000x reference)
//
#include <hip/hip_runtime.h>

#define BB 64
#define SS 512
#define HH 768
#define NSPAN 16
#define PP 240
#define CCOMP 5
#define CREL 3

// ---------------- zero loss accumulators ----------------
__global__ void zero_loss_kernel(float* acc) { acc[threadIdx.x] = 0.0f; }

// ---------------- span mean pooling ----------------
// grid 1024 blocks (b*16+n), 256 threads; each thread 3 H-elems
__global__ __launch_bounds__(256) void pool_kernel(
    const float* __restrict__ lhs, const int* __restrict__ starts,
    const int* __restrict__ lens, float* __restrict__ pooled) {
    int bn = blockIdx.x;
    int b = bn >> 4;
    int st = starts[bn];
    int ln = lens[bn];
    int tid = threadIdx.x;
    const float* base = lhs + ((size_t)b * SS + st) * HH;
    float a0 = 0.f, a1 = 0.f, a2 = 0.f;
    for (int s = 0; s <= ln; ++s) {
        const float* row = base + (size_t)s * HH;
        a0 += row[tid];
        a1 += row[tid + 256];
        a2 += row[tid + 512];
    }
    float inv = 1.0f / (float)(ln + 1);
    float* out = pooled + (size_t)bn * HH;
    out[tid] = a0 * inv;
    out[tid + 256] = a1 * inv;
    out[tid + 512] = a2 * inv;
}

// ---------------- generic 64x64 tile GEMM: C = act(A @ W + bias) ----------------
// A fp32 [.,K] row-major, W fp32 row-major [K, ldw] starting at col wcol0
__device__ __forceinline__ void gemm_tile(
    const float* __restrict__ A, int K,
    const float* __restrict__ W, int ldw, int wcol0,
    const float* __restrict__ bias, int act,
    float* __restrict__ C, int ldc, int ccol0, int row0) {
    __shared__ float As[32][68];  // [k][m], pad 68 (16B-aligned float4 rows)
    __shared__ float Wsm[32][68]; // [k][n]
    int tid = threadIdx.x;
    int tx = tid & 15, ty = tid >> 4;
    float acc[4][4];
#pragma unroll
    for (int i = 0; i < 4; ++i)
#pragma unroll
        for (int j = 0; j < 4; ++j) acc[i][j] = 0.f;

    for (int k0 = 0; k0 < K; k0 += 32) {
#pragma unroll
        for (int l = 0; l < 8; ++l) {
            int idx = tid + l * 256;
            int r = idx >> 5, c = idx & 31;          // A: 64 rows x 32 k
            As[c][r] = A[(size_t)(row0 + r) * K + (k0 + c)];
            int wr = idx >> 6, wc = idx & 63;        // W: 32 k x 64 cols
            Wsm[wr][wc] = W[(size_t)(k0 + wr) * ldw + wcol0 + wc];
        }
        __syncthreads();
#pragma unroll
        for (int k = 0; k < 32; ++k) {
            float4 a4 = *(const float4*)(&As[k][ty * 4]);
            float4 w4 = *(const float4*)(&Wsm[k][tx * 4]);
            float a[4] = {a4.x, a4.y, a4.z, a4.w};
            float w[4] = {w4.x, w4.y, w4.z, w4.w};
#pragma unroll
            for (int i = 0; i < 4; ++i)
#pragma unroll
                for (int j = 0; j < 4; ++j) acc[i][j] = fmaf(a[i], w[j], acc[i][j]);
        }
        __syncthreads();
    }
#pragma unroll
    for (int i = 0; i < 4; ++i) {
        int r = row0 + ty * 4 + i;
#pragma unroll
        for (int j = 0; j < 4; ++j) {
            int c = tx * 4 + j;
            float v = acc[i][j];
            if (bias) v += bias[wcol0 + c];
            if (act) v = tanhf(v);
            C[(size_t)r * ldc + (ccol0 + c)] = v;
        }
    }
}

// fused: y2[1024][2816] = [tanh(pooled@comp_w1+b1) | pooled@wq | pooled@wk | pooled@wv]
__global__ __launch_bounds__(256) void gemm_pw_kernel(
    const float* __restrict__ pooled,
    const float* __restrict__ comp_w1, const float* __restrict__ comp_b1,
    const float* __restrict__ wq, const float* __restrict__ wk, const float* __restrict__ wv,
    float* __restrict__ y2) {
    int ct = blockIdx.x * 64;
    int row0 = blockIdx.y * 64;
    const float* W; const float* bias = nullptr;
    int ldw, wcol0, act;
    if (ct < 512)        { W = comp_w1; ldw = 512; wcol0 = ct;        bias = comp_b1; act = 1; }
    else if (ct < 1280)  { W = wq;      ldw = 768; wcol0 = ct - 512;  act = 0; }
    else if (ct < 2048)  { W = wk;      ldw = 768; wcol0 = ct - 1280; act = 0; }
    else                 { W = wv;      ldw = 768; wcol0 = ct - 2048; act = 0; }
    gemm_tile(pooled, HH, W, ldw, wcol0, bias, act, y2, 2816, ct, row0);
}

// Z[1024][1024] = x @ [W_top | W_bot]   (rel_w1 is [1536,512]; top=rows 0..767, bot=768..1535)
__global__ __launch_bounds__(256) void gemm_z_kernel(
    const float* __restrict__ x, const float* __restrict__ rel_w1, float* __restrict__ Z) {
    int ct = blockIdx.x * 64;
    int row0 = blockIdx.y * 64;
    const float* W = rel_w1 + (ct < 512 ? 0 : (size_t)768 * 512);
    int wcol0 = ct & 511;
    gemm_tile(x, HH, W, 512, wcol0, nullptr, 0, Z, 1024, ct, row0);
}

// ---------------- 16x16 attention + residual + LayerNorm ----------------
// grid 64 blocks (one per batch), 256 threads
__global__ __launch_bounds__(256) void attn_ln_kernel(
    const float* __restrict__ y2, const float* __restrict__ pooled,
    const float* __restrict__ ln_g, const float* __restrict__ ln_b,
    float* __restrict__ x) {
    __shared__ float ks[16][772];   // K tile, then reused for V
    __shared__ float Ssm[16][17];
    int b = blockIdx.x;
    int tid = threadIdx.x;
    int n = tid >> 4;        // 0..15 row
    int hl = tid & 15;       // 0..15 lane-in-row

    // load K[16][768] into LDS
    for (int u = 0; u < 48; ++u) {
        int h = hl + (u << 4);
        ks[n][h] = y2[((size_t)(b * 16 + n)) * 2816 + 1280 + h];
    }
    __syncthreads();

    // scores: thread (n,m) computes dot(q[n], k[m])
    int m = tid & 15;
    const float* qrow = y2 + ((size_t)(b * 16 + n)) * 2816 + 512;
    float dot = 0.f;
    for (int h = 0; h < 768; h += 4) {
        float4 qv = *(const float4*)(qrow + h);
        float4 kv = *(const float4*)(&ks[m][h]);
        dot += qv.x * kv.x + qv.y * kv.y + qv.z * kv.z + qv.w * kv.w;
    }
    float sval = dot * 0.03608439182435161f;  // 1/sqrt(768)
    float mx = sval;
#pragma unroll
    for (int off = 8; off >= 1; off >>= 1) mx = fmaxf(mx, __shfl_xor(mx, off, 16));
    float pexp = __expf(sval - mx);
    float psum = pexp;
#pragma unroll
    for (int off = 8; off >= 1; off >>= 1) psum += __shfl_xor(psum, off, 16);
    Ssm[n][m] = pexp / psum;
    __syncthreads();

    // reload LDS with V
    for (int u = 0; u < 48; ++u) {
        int h = hl + (u << 4);
        ks[n][h] = y2[((size_t)(b * 16 + n)) * 2816 + 2048 + h];
    }
    __syncthreads();

    // attn + residual + LN; thread (n, hl) handles 48 h-values
    float sc[16];
#pragma unroll
    for (int mm = 0; mm < 16; ++mm) sc[mm] = Ssm[n][mm];
    int row = b * 16 + n;
    const float* prow = pooled + (size_t)row * HH;
    float xv[48];
    float ssum = 0.f, ssq = 0.f;
    for (int u = 0; u < 48; ++u) {
        int h = hl + (u << 4);
        float a = 0.f;
#pragma unroll
        for (int mm = 0; mm < 16; ++mm) a += sc[mm] * ks[mm][h];
        float v = prow[h] + a;
        xv[u] = v;
        ssum += v;
        ssq += v * v;
    }
#pragma unroll
    for (int off = 8; off >= 1; off >>= 1) {
        ssum += __shfl_xor(ssum, off, 16);
        ssq += __shfl_xor(ssq, off, 16);
    }
    float mu = ssum * (1.0f / 768.0f);
    float var = ssq * (1.0f / 768.0f) - mu * mu;
    float rs = rsqrtf(var + 1e-5f);
    float* xrow = x + (size_t)row * HH;
    for (int u = 0; u < 48; ++u) {
        int h = hl + (u << 4);
        xrow[h] = (xv[u] - mu) * rs * ln_g[h] + ln_b[h];
    }
}

// ---------------- comp head: logits + CE ----------------
// wave per row; grid 256 blocks x 4 waves = 1024 rows
__global__ __launch_bounds__(256) void comp_head_kernel(
    const float* __restrict__ y2, const float* __restrict__ w2,
    const float* __restrict__ b2, const int* __restrict__ gold,
    float* __restrict__ out, float* __restrict__ loss_acc) {
    int wave = threadIdx.x >> 6, lane = threadIdx.x & 63;
    int row = blockIdx.x * 4 + wave;
    const float* hrow = y2 + (size_t)row * 2816;
    float acc[CCOMP] = {0.f, 0.f, 0.f, 0.f, 0.f};
#pragma unroll
    for (int t = 0; t < 8; ++t) {
        int c = lane + (t << 6);
        float h = hrow[c];
#pragma unroll
        for (int cc = 0; cc < CCOMP; ++cc) acc[cc] += h * w2[c * CCOMP + cc];
    }
#pragma unroll
    for (int cc = 0; cc < CCOMP; ++cc)
#pragma unroll
        for (int off = 32; off >= 1; off >>= 1) acc[cc] += __shfl_down(acc[cc], off);
    if (lane == 0) {
        float l[CCOMP];
        float mx = -1e30f;
#pragma unroll
        for (int cc = 0; cc < CCOMP; ++cc) { l[cc] = acc[cc] + b2[cc]; mx = fmaxf(mx, l[cc]); }
        float se = 0.f;
#pragma unroll
        for (int cc = 0; cc < CCOMP; ++cc) se += __expf(l[cc] - mx);
        float lse = __logf(se) + mx;
        atomicAdd(loss_acc, lse - l[gold[row]]);
#pragma unroll
        for (int cc = 0; cc < CCOMP; ++cc) out[row * CCOMP + cc] = l[cc];
    }
}

// ---------------- rel head: h=tanh(Z1[i]+Z2[j]+b1); logits=h@w2+b2; CE ----------------
// wave per pair-row; grid 3840 blocks x 4 waves = 15360 rows
__global__ __launch_bounds__(256) void rel_head_kernel(
    const float* __restrict__ Z, const float* __restrict__ b1,
    const float* __restrict__ w2, const float* __restrict__ b2,
    const int* __restrict__ gold, float* __restrict__ out,
    float* __restrict__ loss_acc) {
    int wave = threadIdx.x >> 6, lane = threadIdx.x & 63;
    int row = blockIdx.x * 4 + wave;   // 0..15359
    int b = row / PP;
    int p = row - b * PP;
    int i = p / 15;
    int jj = p - i * 15;
    int j = jj + (jj >= i ? 1 : 0);
    const float* z1 = Z + ((size_t)(b * 16 + i)) * 1024;
    const float* z2 = Z + ((size_t)(b * 16 + j)) * 1024 + 512;
    float a0 = 0.f, a1 = 0.f, a2 = 0.f;
#pragma unroll
    for (int t = 0; t < 8; ++t) {
        int c = lane + (t << 6);
        float h = tanhf(z1[c] + z2[c] + b1[c]);
        a0 += h * w2[c * 3 + 0];
        a1 += h * w2[c * 3 + 1];
        a2 += h * w2[c * 3 + 2];
    }
#pragma unroll
    for (int off = 32; off >= 1; off >>= 1) {
        a0 += __shfl_down(a0, off);
        a1 += __shfl_down(a1, off);
        a2 += __shfl_down(a2, off);
    }
    if (lane == 0) {
        float l0 = a0 + b2[0];
        float l1 = a1 + b2[1];
        float l2 = a2 + b2[2];
        float mx = fmaxf(l0, fmaxf(l1, l2));
        float se = __expf(l0 - mx) + __expf(l1 - mx) + __expf(l2 - mx);
        float lse = __logf(se) + mx;
        int g = gold[row];
        float lg = (g == 0) ? l0 : ((g == 1) ? l1 : l2);
        atomicAdd(loss_acc, lse - lg);
        out[row * 3 + 0] = l0;
        out[row * 3 + 1] = l1;
        out[row * 3 + 2] = l2;
    }
}

__global__ void finalize_kernel(const float* __restrict__ acc, float* __restrict__ out) {
    out[51200] = acc[0] * (1.0f / 1024.0f);
    out[51201] = acc[1] * (1.0f / 15360.0f);
}

extern "C" void kernel_launch(void* const* d_in, const int* in_sizes, int n_in,
                              void* d_out, int out_size, void* d_ws, size_t ws_size,
                              hipStream_t stream) {
    const float* lhs     = (const float*)d_in[0];
    const int* starts    = (const int*)d_in[1];
    const int* lens      = (const int*)d_in[2];
    const int* comps     = (const int*)d_in[3];
    const int* rels      = (const int*)d_in[4];
    const float* comp_w1 = (const float*)d_in[5];
    const float* comp_b1 = (const float*)d_in[6];
    const float* comp_w2 = (const float*)d_in[7];
    const float* comp_b2 = (const float*)d_in[8];
    const float* wq      = (const float*)d_in[9];
    const float* wk      = (const float*)d_in[10];
    const float* wv      = (const float*)d_in[11];
    const float* ln_g    = (const float*)d_in[12];
    const float* ln_b    = (const float*)d_in[13];
    const float* rel_w1  = (const float*)d_in[14];
    const float* rel_b1  = (const float*)d_in[15];
    const float* rel_w2  = (const float*)d_in[16];
    const float* rel_b2  = (const float*)d_in[17];
    float* out = (float*)d_out;
    float* ws = (float*)d_ws;

    float* pooled = ws;                       // 1024*768   = 786432
    float* y2     = pooled + 786432;          // 1024*2816  = 2883584
    float* x      = y2 + 2883584;             // 1024*768   = 786432
    float* Z      = x + 786432;               // 1024*1024  = 1048576
    float* loss   = Z + 1048576;              // 2

    zero_loss_kernel<<<1, 2, 0, stream>>>(loss);
    pool_kernel<<<1024, 256, 0, stream>>>(lhs, starts, lens, pooled);
    gemm_pw_kernel<<<dim3(44, 16), 256, 0, stream>>>(pooled, comp_w1, comp_b1, wq, wk, wv, y2);
    attn_ln_kernel<<<64, 256, 0, stream>>>(y2, pooled, ln_g, ln_b, x);
    gemm_z_kernel<<<dim3(16, 16), 256, 0, stream>>>(x, rel_w1, Z);
    comp_head_kernel<<<256, 256, 0, stream>>>(y2, comp_w2, comp_b2, comps, out, loss);
    rel_head_kernel<<<3840, 256, 0, stream>>>(Z, rel_b1, rel_w2, rel_b2, rels, out + 5120, loss + 1);
    finalize_kernel<<<1, 1, 0, stream>>>(loss, out);
}

// Round 4
// 334.249 us; speedup vs baseline: 1.6133x; 1.6133x over previous
//
#include <hip/hip_runtime.h>

#define BB 64
#define SS 512
#define HH 768
#define NSPAN 16
#define PP 240
#define CCOMP 5
#define CREL 3

// ---------------- span mean pooling ----------------
// grid 1024 blocks (b*16+n), 256 threads; each thread 3 H-elems
__global__ __launch_bounds__(256) void pool_kernel(
    const float* __restrict__ lhs, const int* __restrict__ starts,
    const int* __restrict__ lens, float* __restrict__ pooled) {
    int bn = blockIdx.x;
    int b = bn >> 4;
    int st = starts[bn];
    int ln = lens[bn];
    int tid = threadIdx.x;
    const float* base = lhs + ((size_t)b * SS + st) * HH;
    float a0 = 0.f, a1 = 0.f, a2 = 0.f;
    for (int s = 0; s <= ln; ++s) {
        const float* row = base + (size_t)s * HH;
        a0 += row[tid];
        a1 += row[tid + 256];
        a2 += row[tid + 512];
    }
    float inv = 1.0f / (float)(ln + 1);
    float* out = pooled + (size_t)bn * HH;
    out[tid] = a0 * inv;
    out[tid + 256] = a1 * inv;
    out[tid + 512] = a2 * inv;
}

// ---------------- generic 64x64 tile GEMM: C = act(A @ W + bias) ----------------
// A fp32 [.,K] row-major, W fp32 row-major [K, ldw] starting at col wcol0
__device__ __forceinline__ void gemm_tile(
    const float* __restrict__ A, int K,
    const float* __restrict__ W, int ldw, int wcol0,
    const float* __restrict__ bias, int act,
    float* __restrict__ C, int ldc, int ccol0, int row0) {
    __shared__ float As[32][68];  // [k][m], pad 68 (16B-aligned float4 rows)
    __shared__ float Wsm[32][68]; // [k][n]
    int tid = threadIdx.x;
    int tx = tid & 15, ty = tid >> 4;
    float acc[4][4];
#pragma unroll
    for (int i = 0; i < 4; ++i)
#pragma unroll
        for (int j = 0; j < 4; ++j) acc[i][j] = 0.f;

    for (int k0 = 0; k0 < K; k0 += 32) {
#pragma unroll
        for (int l = 0; l < 8; ++l) {
            int idx = tid + l * 256;
            int r = idx >> 5, c = idx & 31;          // A: 64 rows x 32 k
            As[c][r] = A[(size_t)(row0 + r) * K + (k0 + c)];
            int wr = idx >> 6, wc = idx & 63;        // W: 32 k x 64 cols
            Wsm[wr][wc] = W[(size_t)(k0 + wr) * ldw + wcol0 + wc];
        }
        __syncthreads();
#pragma unroll
        for (int k = 0; k < 32; ++k) {
            float4 a4 = *(const float4*)(&As[k][ty * 4]);
            float4 w4 = *(const float4*)(&Wsm[k][tx * 4]);
            float a[4] = {a4.x, a4.y, a4.z, a4.w};
            float w[4] = {w4.x, w4.y, w4.z, w4.w};
#pragma unroll
            for (int i = 0; i < 4; ++i)
#pragma unroll
                for (int j = 0; j < 4; ++j) acc[i][j] = fmaf(a[i], w[j], acc[i][j]);
        }
        __syncthreads();
    }
#pragma unroll
    for (int i = 0; i < 4; ++i) {
        int r = row0 + ty * 4 + i;
#pragma unroll
        for (int j = 0; j < 4; ++j) {
            int c = tx * 4 + j;
            float v = acc[i][j];
            if (bias) v += bias[wcol0 + c];
            if (act) v = tanhf(v);
            C[(size_t)r * ldc + (ccol0 + c)] = v;
        }
    }
}

// fused: y2[1024][2816] = [tanh(pooled@comp_w1+b1) | pooled@wq | pooled@wk | pooled@wv]
__global__ __launch_bounds__(256) void gemm_pw_kernel(
    const float* __restrict__ pooled,
    const float* __restrict__ comp_w1, const float* __restrict__ comp_b1,
    const float* __restrict__ wq, const float* __restrict__ wk, const float* __restrict__ wv,
    float* __restrict__ y2) {
    int ct = blockIdx.x * 64;
    int row0 = blockIdx.y * 64;
    const float* W; const float* bias = nullptr;
    int ldw, wcol0, act;
    if (ct < 512)        { W = comp_w1; ldw = 512; wcol0 = ct;        bias = comp_b1; act = 1; }
    else if (ct < 1280)  { W = wq;      ldw = 768; wcol0 = ct - 512;  act = 0; }
    else if (ct < 2048)  { W = wk;      ldw = 768; wcol0 = ct - 1280; act = 0; }
    else                 { W = wv;      ldw = 768; wcol0 = ct - 2048; act = 0; }
    gemm_tile(pooled, HH, W, ldw, wcol0, bias, act, y2, 2816, ct, row0);
}

// Z[1024][1024] = x @ [W_top | W_bot]   (rel_w1 is [1536,512]; top=rows 0..767, bot=768..1535)
__global__ __launch_bounds__(256) void gemm_z_kernel(
    const float* __restrict__ x, const float* __restrict__ rel_w1, float* __restrict__ Z) {
    int ct = blockIdx.x * 64;
    int row0 = blockIdx.y * 64;
    const float* W = rel_w1 + (ct < 512 ? 0 : (size_t)768 * 512);
    int wcol0 = ct & 511;
    gemm_tile(x, HH, W, 512, wcol0, nullptr, 0, Z, 1024, ct, row0);
}

// ---------------- 16x16 attention + residual + LayerNorm ----------------
// grid 64 blocks (one per batch), 256 threads
__global__ __launch_bounds__(256) void attn_ln_kernel(
    const float* __restrict__ y2, const float* __restrict__ pooled,
    const float* __restrict__ ln_g, const float* __restrict__ ln_b,
    float* __restrict__ x) {
    __shared__ float ks[16][772];   // K tile, then reused for V
    __shared__ float Ssm[16][17];
    int b = blockIdx.x;
    int tid = threadIdx.x;
    int n = tid >> 4;        // 0..15 row
    int hl = tid & 15;       // 0..15 lane-in-row

    // load K[16][768] into LDS
    for (int u = 0; u < 48; ++u) {
        int h = hl + (u << 4);
        ks[n][h] = y2[((size_t)(b * 16 + n)) * 2816 + 1280 + h];
    }
    __syncthreads();

    // scores: thread (n,m) computes dot(q[n], k[m])
    int m = tid & 15;
    const float* qrow = y2 + ((size_t)(b * 16 + n)) * 2816 + 512;
    float dot = 0.f;
    for (int h = 0; h < 768; h += 4) {
        float4 qv = *(const float4*)(qrow + h);
        float4 kv = *(const float4*)(&ks[m][h]);
        dot += qv.x * kv.x + qv.y * kv.y + qv.z * kv.z + qv.w * kv.w;
    }
    float sval = dot * 0.03608439182435161f;  // 1/sqrt(768)
    float mx = sval;
#pragma unroll
    for (int off = 8; off >= 1; off >>= 1) mx = fmaxf(mx, __shfl_xor(mx, off, 16));
    float pexp = __expf(sval - mx);
    float psum = pexp;
#pragma unroll
    for (int off = 8; off >= 1; off >>= 1) psum += __shfl_xor(psum, off, 16);
    Ssm[n][m] = pexp / psum;
    __syncthreads();

    // reload LDS with V
    for (int u = 0; u < 48; ++u) {
        int h = hl + (u << 4);
        ks[n][h] = y2[((size_t)(b * 16 + n)) * 2816 + 2048 + h];
    }
    __syncthreads();

    // attn + residual + LN; thread (n, hl) handles 48 h-values
    float sc[16];
#pragma unroll
    for (int mm = 0; mm < 16; ++mm) sc[mm] = Ssm[n][mm];
    int row = b * 16 + n;
    const float* prow = pooled + (size_t)row * HH;
    float xv[48];
    float ssum = 0.f, ssq = 0.f;
    for (int u = 0; u < 48; ++u) {
        int h = hl + (u << 4);
        float a = 0.f;
#pragma unroll
        for (int mm = 0; mm < 16; ++mm) a += sc[mm] * ks[mm][h];
        float v = prow[h] + a;
        xv[u] = v;
        ssum += v;
        ssq += v * v;
    }
#pragma unroll
    for (int off = 8; off >= 1; off >>= 1) {
        ssum += __shfl_xor(ssum, off, 16);
        ssq += __shfl_xor(ssq, off, 16);
    }
    float mu = ssum * (1.0f / 768.0f);
    float var = ssq * (1.0f / 768.0f) - mu * mu;
    float rs = rsqrtf(var + 1e-5f);
    float* xrow = x + (size_t)row * HH;
    for (int u = 0; u < 48; ++u) {
        int h = hl + (u << 4);
        xrow[h] = (xv[u] - mu) * rs * ln_g[h] + ln_b[h];
    }
}

// ---------------- comp head: logits + CE (block-partial loss, no atomics) ----------------
// wave per row; grid 256 blocks x 4 waves = 1024 rows
__global__ __launch_bounds__(256) void comp_head_kernel(
    const float* __restrict__ y2, const float* __restrict__ w2,
    const float* __restrict__ b2, const int* __restrict__ gold,
    float* __restrict__ out, float* __restrict__ partial) {
    __shared__ float red[4];
    int wave = threadIdx.x >> 6, lane = threadIdx.x & 63;
    int row = blockIdx.x * 4 + wave;
    const float* hrow = y2 + (size_t)row * 2816;
    float acc[CCOMP] = {0.f, 0.f, 0.f, 0.f, 0.f};
#pragma unroll
    for (int t = 0; t < 8; ++t) {
        int c = lane + (t << 6);
        float h = hrow[c];
#pragma unroll
        for (int cc = 0; cc < CCOMP; ++cc) acc[cc] += h * w2[c * CCOMP + cc];
    }
#pragma unroll
    for (int cc = 0; cc < CCOMP; ++cc)
#pragma unroll
        for (int off = 32; off >= 1; off >>= 1) acc[cc] += __shfl_down(acc[cc], off);
    if (lane == 0) {
        float l[CCOMP];
        float mx = -1e30f;
#pragma unroll
        for (int cc = 0; cc < CCOMP; ++cc) { l[cc] = acc[cc] + b2[cc]; mx = fmaxf(mx, l[cc]); }
        float se = 0.f;
#pragma unroll
        for (int cc = 0; cc < CCOMP; ++cc) se += __expf(l[cc] - mx);
        float lse = __logf(se) + mx;
        red[wave] = lse - l[gold[row]];
#pragma unroll
        for (int cc = 0; cc < CCOMP; ++cc) out[row * CCOMP + cc] = l[cc];
    }
    __syncthreads();
    if (threadIdx.x == 0) partial[blockIdx.x] = red[0] + red[1] + red[2] + red[3];
}

// ---------------- rel head: h=tanh(Z1[i]+Z2[j]+b1); logits=h@w2+b2; CE ----------------
// wave per pair-row; grid 3840 blocks x 4 waves = 15360 rows; block-partial loss
__global__ __launch_bounds__(256) void rel_head_kernel(
    const float* __restrict__ Z, const float* __restrict__ b1,
    const float* __restrict__ w2, const float* __restrict__ b2,
    const int* __restrict__ gold, float* __restrict__ out,
    float* __restrict__ partial) {
    __shared__ float red[4];
    int wave = threadIdx.x >> 6, lane = threadIdx.x & 63;
    int row = blockIdx.x * 4 + wave;   // 0..15359
    int b = row / PP;
    int p = row - b * PP;
    int i = p / 15;
    int jj = p - i * 15;
    int j = jj + (jj >= i ? 1 : 0);
    const float* z1 = Z + ((size_t)(b * 16 + i)) * 1024;
    const float* z2 = Z + ((size_t)(b * 16 + j)) * 1024 + 512;
    float a0 = 0.f, a1 = 0.f, a2 = 0.f;
#pragma unroll
    for (int t = 0; t < 8; ++t) {
        int c = lane + (t << 6);
        float h = tanhf(z1[c] + z2[c] + b1[c]);
        a0 += h * w2[c * 3 + 0];
        a1 += h * w2[c * 3 + 1];
        a2 += h * w2[c * 3 + 2];
    }
#pragma unroll
    for (int off = 32; off >= 1; off >>= 1) {
        a0 += __shfl_down(a0, off);
        a1 += __shfl_down(a1, off);
        a2 += __shfl_down(a2, off);
    }
    if (lane == 0) {
        float l0 = a0 + b2[0];
        float l1 = a1 + b2[1];
        float l2 = a2 + b2[2];
        float mx = fmaxf(l0, fmaxf(l1, l2));
        float se = __expf(l0 - mx) + __expf(l1 - mx) + __expf(l2 - mx);
        float lse = __logf(se) + mx;
        int g = gold[row];
        float lg = (g == 0) ? l0 : ((g == 1) ? l1 : l2);
        red[wave] = lse - lg;
        out[row * 3 + 0] = l0;
        out[row * 3 + 1] = l1;
        out[row * 3 + 2] = l2;
    }
    __syncthreads();
    if (threadIdx.x == 0) partial[blockIdx.x] = red[0] + red[1] + red[2] + red[3];
}

// ---------------- final loss reduction: 256 comp partials + 3840 rel partials ----------------
__global__ __launch_bounds__(256) void finalize_kernel(
    const float* __restrict__ comp_p, const float* __restrict__ rel_p,
    float* __restrict__ out) {
    __shared__ float rc[4], rr[4];
    int tid = threadIdx.x;
    int wave = tid >> 6, lane = tid & 63;
    float sc = comp_p[tid];
    float sr = 0.f;
#pragma unroll
    for (int k = 0; k < 15; ++k) sr += rel_p[tid + k * 256];
#pragma unroll
    for (int off = 32; off >= 1; off >>= 1) {
        sc += __shfl_down(sc, off);
        sr += __shfl_down(sr, off);
    }
    if (lane == 0) { rc[wave] = sc; rr[wave] = sr; }
    __syncthreads();
    if (tid == 0) {
        out[51200] = (rc[0] + rc[1] + rc[2] + rc[3]) * (1.0f / 1024.0f);
        out[51201] = (rr[0] + rr[1] + rr[2] + rr[3]) * (1.0f / 15360.0f);
    }
}

extern "C" void kernel_launch(void* const* d_in, const int* in_sizes, int n_in,
                              void* d_out, int out_size, void* d_ws, size_t ws_size,
                              hipStream_t stream) {
    const float* lhs     = (const float*)d_in[0];
    const int* starts    = (const int*)d_in[1];
    const int* lens      = (const int*)d_in[2];
    const int* comps     = (const int*)d_in[3];
    const int* rels      = (const int*)d_in[4];
    const float* comp_w1 = (const float*)d_in[5];
    const float* comp_b1 = (const float*)d_in[6];
    const float* comp_w2 = (const float*)d_in[7];
    const float* comp_b2 = (const float*)d_in[8];
    const float* wq      = (const float*)d_in[9];
    const float* wk      = (const float*)d_in[10];
    const float* wv      = (const float*)d_in[11];
    const float* ln_g    = (const float*)d_in[12];
    const float* ln_b    = (const float*)d_in[13];
    const float* rel_w1  = (const float*)d_in[14];
    const float* rel_b1  = (const float*)d_in[15];
    const float* rel_w2  = (const float*)d_in[16];
    const float* rel_b2  = (const float*)d_in[17];
    float* out = (float*)d_out;
    float* ws = (float*)d_ws;

    float* pooled = ws;                       // 1024*768   = 786432
    float* y2     = pooled + 786432;          // 1024*2816  = 2883584
    float* x      = y2 + 2883584;             // 1024*768   = 786432
    float* Z      = x + 786432;               // 1024*1024  = 1048576
    float* comp_p = Z + 1048576;              // 256
    float* rel_p  = comp_p + 256;             // 3840

    pool_kernel<<<1024, 256, 0, stream>>>(lhs, starts, lens, pooled);
    gemm_pw_kernel<<<dim3(44, 16), 256, 0, stream>>>(pooled, comp_w1, comp_b1, wq, wk, wv, y2);
    attn_ln_kernel<<<64, 256, 0, stream>>>(y2, pooled, ln_g, ln_b, x);
    gemm_z_kernel<<<dim3(16, 16), 256, 0, stream>>>(x, rel_w1, Z);
    comp_head_kernel<<<256, 256, 0, stream>>>(y2, comp_w2, comp_b2, comps, out, comp_p);
    rel_head_kernel<<<3840, 256, 0, stream>>>(Z, rel_b1, rel_w2, rel_b2, rels, out + 5120, rel_p);
    finalize_kernel<<<1, 256, 0, stream>>>(comp_p, rel_p, out);
}

// Round 5
// 252.216 us; speedup vs baseline: 2.1381x; 1.3252x over previous
//
#include <hip/hip_runtime.h>

#define BB 64
#define SS 512
#define HH 768
#define NSPAN 16
#define PP 240
#define CCOMP 5
#define CREL 3

typedef unsigned short u16;
typedef __attribute__((ext_vector_type(8))) short bf16x8;   // 8 bf16 in 4 VGPRs
typedef __attribute__((ext_vector_type(4))) float f32x4;

__device__ __forceinline__ u16 f2bf(float f) {
    union { float f; unsigned int i; } v; v.f = f;
    unsigned int x = v.i;
    unsigned int lsb = (x >> 16) & 1u;
    x += 0x7fffu + lsb;
    return (u16)(x >> 16);
}

// ---------------- weight prep: bf16 + transpose to [n][k] (K=768 contiguous) ----------------
// 32x32 tiles via LDS. Block map: comp_w1(384) wq(576) wk(576) wv(576) rel_top(384) rel_bot(384)
__global__ __launch_bounds__(256) void prep_kernel(
    const float* __restrict__ cw1, const float* __restrict__ wq,
    const float* __restrict__ wk, const float* __restrict__ wv,
    const float* __restrict__ rw1, u16* __restrict__ wcat_t, u16* __restrict__ relw_t) {
    int blk = blockIdx.x;
    const float* W; int ldw, nt; u16* outp;
    if (blk < 384)        {             W = cw1; ldw = 512; nt = 16; outp = wcat_t; }
    else if (blk < 960)   { blk -= 384; W = wq;  ldw = 768; nt = 24; outp = wcat_t + (size_t)512 * 768; }
    else if (blk < 1536)  { blk -= 960; W = wk;  ldw = 768; nt = 24; outp = wcat_t + (size_t)1280 * 768; }
    else if (blk < 2112)  { blk -= 1536; W = wv; ldw = 768; nt = 24; outp = wcat_t + (size_t)2048 * 768; }
    else if (blk < 2496)  { blk -= 2112; W = rw1; ldw = 512; nt = 16; outp = relw_t; }
    else                  { blk -= 2496; W = rw1 + (size_t)768 * 512; ldw = 512; nt = 16; outp = relw_t + (size_t)512 * 768; }
    int tk = blk / nt, tn = blk % nt;
    int k0 = tk * 32, n0 = tn * 32;
    __shared__ u16 Ls[32][36];   // [n][k], pad 36 (2-way max = free)
    int tid = threadIdx.x;
    int tx = tid & 31, ty = tid >> 5;
#pragma unroll
    for (int r = 0; r < 4; ++r) {
        int k = ty + r * 8;
        Ls[tx][k] = f2bf(W[(size_t)(k0 + k) * ldw + n0 + tx]);
    }
    __syncthreads();
#pragma unroll
    for (int r = 0; r < 4; ++r) {
        int n = ty + r * 8;
        outp[(size_t)(n0 + n) * 768 + k0 + tx] = Ls[n][tx];
    }
}

// ---------------- span mean pooling (fp32 + bf16 outputs) ----------------
__global__ __launch_bounds__(256) void pool_kernel(
    const float* __restrict__ lhs, const int* __restrict__ starts,
    const int* __restrict__ lens, float* __restrict__ pooled, u16* __restrict__ pooled_bf) {
    int bn = blockIdx.x;
    int b = bn >> 4;
    int st = starts[bn];
    int ln = lens[bn];
    int tid = threadIdx.x;
    const float* base = lhs + ((size_t)b * SS + st) * HH;
    float a0 = 0.f, a1 = 0.f, a2 = 0.f;
    for (int s = 0; s <= ln; ++s) {
        const float* row = base + (size_t)s * HH;
        a0 += row[tid];
        a1 += row[tid + 256];
        a2 += row[tid + 512];
    }
    float inv = 1.0f / (float)(ln + 1);
    a0 *= inv; a1 *= inv; a2 *= inv;
    float* out = pooled + (size_t)bn * HH;
    u16* outb = pooled_bf + (size_t)bn * HH;
    out[tid] = a0;       out[tid + 256] = a1;       out[tid + 512] = a2;
    outb[tid] = f2bf(a0); outb[tid + 256] = f2bf(a1); outb[tid + 512] = f2bf(a2);
}

// ---------------- MFMA bf16 GEMM: C[row][col] = act(A@B^T + bias) ----------------
// A: bf16 [M][768] rows at row0; Bt: bf16 [N][768] rows at ccol0 (i.e. W^T, K-contiguous)
// 64x64 block tile, 4 waves x 32x32, BK=64, fp32 accum.
__device__ __forceinline__ void gemm_mfma_tile(
    const u16* __restrict__ A, const u16* __restrict__ Bt,
    float* __restrict__ C, int ldc, int row0, int ccol0,
    const float* __restrict__ bias, int act) {
    __shared__ u16 As[64][72];
    __shared__ u16 Bs[64][72];
    int tid = threadIdx.x;
    int lane = tid & 63, w = tid >> 6;
    int q = lane >> 4, l15 = lane & 15;
    int wm = (w & 1) * 32, wn = (w >> 1) * 32;
    int r = tid >> 2, c0 = (tid & 3) * 16;
    const u16* ga = A + (size_t)(row0 + r) * 768 + c0;
    const u16* gb = Bt + (size_t)(ccol0 + r) * 768 + c0;
    f32x4 acc[2][2];
#pragma unroll
    for (int i = 0; i < 2; ++i)
#pragma unroll
        for (int j = 0; j < 2; ++j) acc[i][j] = (f32x4){0.f, 0.f, 0.f, 0.f};

    for (int k0 = 0; k0 < 768; k0 += 64) {
        uint4 va0 = *(const uint4*)(ga + k0);
        uint4 va1 = *(const uint4*)(ga + k0 + 8);
        uint4 vb0 = *(const uint4*)(gb + k0);
        uint4 vb1 = *(const uint4*)(gb + k0 + 8);
        __syncthreads();   // previous iteration's LDS reads complete
        *(uint4*)(&As[r][c0]) = va0;
        *(uint4*)(&As[r][c0 + 8]) = va1;
        *(uint4*)(&Bs[r][c0]) = vb0;
        *(uint4*)(&Bs[r][c0 + 8]) = vb1;
        __syncthreads();
#pragma unroll
        for (int ks = 0; ks < 2; ++ks) {
            bf16x8 a0 = *(const bf16x8*)(&As[wm + l15][ks * 32 + q * 8]);
            bf16x8 a1 = *(const bf16x8*)(&As[wm + 16 + l15][ks * 32 + q * 8]);
            bf16x8 b0 = *(const bf16x8*)(&Bs[wn + l15][ks * 32 + q * 8]);
            bf16x8 b1 = *(const bf16x8*)(&Bs[wn + 16 + l15][ks * 32 + q * 8]);
            acc[0][0] = __builtin_amdgcn_mfma_f32_16x16x32_bf16(a0, b0, acc[0][0], 0, 0, 0);
            acc[0][1] = __builtin_amdgcn_mfma_f32_16x16x32_bf16(a0, b1, acc[0][1], 0, 0, 0);
            acc[1][0] = __builtin_amdgcn_mfma_f32_16x16x32_bf16(a1, b0, acc[1][0], 0, 0, 0);
            acc[1][1] = __builtin_amdgcn_mfma_f32_16x16x32_bf16(a1, b1, acc[1][1], 0, 0, 0);
        }
    }
    // epilogue: C/D layout col=lane&15, row=(lane>>4)*4+reg  [m89-verified]
#pragma unroll
    for (int tm = 0; tm < 2; ++tm)
#pragma unroll
        for (int tn = 0; tn < 2; ++tn)
#pragma unroll
            for (int reg = 0; reg < 4; ++reg) {
                int rr = row0 + wm + tm * 16 + q * 4 + reg;
                int cc = ccol0 + wn + tn * 16 + l15;
                float v = acc[tm][tn][reg];
                if (bias) v += bias[cc];
                if (act) v = tanhf(v);
                C[(size_t)rr * ldc + cc] = v;
            }
}

// y2[1024][2816] = [tanh(pooled@comp_w1+b1) | q | k | v]
__global__ __launch_bounds__(256) void gemm_pw_kernel(
    const u16* __restrict__ pooled_bf, const u16* __restrict__ wcat_t,
    const float* __restrict__ comp_b1, float* __restrict__ y2) {
    int ccol0 = blockIdx.x * 64;
    int row0 = blockIdx.y * 64;
    int act = (ccol0 < 512);
    gemm_mfma_tile(pooled_bf, wcat_t, y2, 2816, row0, ccol0, act ? comp_b1 : nullptr, act);
}

// Z[1024][1024] = x @ [W_top | W_bot]
__global__ __launch_bounds__(256) void gemm_z_kernel(
    const u16* __restrict__ x_bf, const u16* __restrict__ relw_t, float* __restrict__ Z) {
    int ccol0 = blockIdx.x * 64;
    int row0 = blockIdx.y * 64;
    gemm_mfma_tile(x_bf, relw_t, Z, 1024, row0, ccol0, nullptr, 0);
}

// ---------------- 16x16 attention + residual + LayerNorm ----------------
__global__ __launch_bounds__(256) void attn_ln_kernel(
    const float* __restrict__ y2, const float* __restrict__ pooled,
    const float* __restrict__ ln_g, const float* __restrict__ ln_b,
    float* __restrict__ x, u16* __restrict__ x_bf) {
    __shared__ float ks[16][772];   // K tile, then reused for V
    __shared__ float Ssm[16][17];
    int b = blockIdx.x;
    int tid = threadIdx.x;
    int n = tid >> 4;
    int hl = tid & 15;

    for (int u = 0; u < 48; ++u) {
        int h = hl + (u << 4);
        ks[n][h] = y2[((size_t)(b * 16 + n)) * 2816 + 1280 + h];
    }
    __syncthreads();

    int m = tid & 15;
    const float* qrow = y2 + ((size_t)(b * 16 + n)) * 2816 + 512;
    float dot = 0.f;
    for (int h = 0; h < 768; h += 4) {
        float4 qv = *(const float4*)(qrow + h);
        float4 kv = *(const float4*)(&ks[m][h]);
        dot += qv.x * kv.x + qv.y * kv.y + qv.z * kv.z + qv.w * kv.w;
    }
    float sval = dot * 0.03608439182435161f;  // 1/sqrt(768)
    float mx = sval;
#pragma unroll
    for (int off = 8; off >= 1; off >>= 1) mx = fmaxf(mx, __shfl_xor(mx, off, 16));
    float pexp = __expf(sval - mx);
    float psum = pexp;
#pragma unroll
    for (int off = 8; off >= 1; off >>= 1) psum += __shfl_xor(psum, off, 16);
    Ssm[n][m] = pexp / psum;
    __syncthreads();

    for (int u = 0; u < 48; ++u) {
        int h = hl + (u << 4);
        ks[n][h] = y2[((size_t)(b * 16 + n)) * 2816 + 2048 + h];
    }
    __syncthreads();

    float sc[16];
#pragma unroll
    for (int mm = 0; mm < 16; ++mm) sc[mm] = Ssm[n][mm];
    int row = b * 16 + n;
    const float* prow = pooled + (size_t)row * HH;
    float xv[48];
    float ssum = 0.f, ssq = 0.f;
    for (int u = 0; u < 48; ++u) {
        int h = hl + (u << 4);
        float a = 0.f;
#pragma unroll
        for (int mm = 0; mm < 16; ++mm) a += sc[mm] * ks[mm][h];
        float v = prow[h] + a;
        xv[u] = v;
        ssum += v;
        ssq += v * v;
    }
#pragma unroll
    for (int off = 8; off >= 1; off >>= 1) {
        ssum += __shfl_xor(ssum, off, 16);
        ssq += __shfl_xor(ssq, off, 16);
    }
    float mu = ssum * (1.0f / 768.0f);
    float var = ssq * (1.0f / 768.0f) - mu * mu;
    float rs = rsqrtf(var + 1e-5f);
    float* xrow = x + (size_t)row * HH;
    u16* xrow_bf = x_bf + (size_t)row * HH;
    for (int u = 0; u < 48; ++u) {
        int h = hl + (u << 4);
        float v = (xv[u] - mu) * rs * ln_g[h] + ln_b[h];
        xrow[h] = v;
        xrow_bf[h] = f2bf(v);
    }
}

// ---------------- comp head: logits + CE (block-partial loss) ----------------
__global__ __launch_bounds__(256) void comp_head_kernel(
    const float* __restrict__ y2, const float* __restrict__ w2,
    const float* __restrict__ b2, const int* __restrict__ gold,
    float* __restrict__ out, float* __restrict__ partial) {
    __shared__ float red[4];
    int wave = threadIdx.x >> 6, lane = threadIdx.x & 63;
    int row = blockIdx.x * 4 + wave;
    const float* hrow = y2 + (size_t)row * 2816;
    float acc[CCOMP] = {0.f, 0.f, 0.f, 0.f, 0.f};
#pragma unroll
    for (int t = 0; t < 8; ++t) {
        int c = lane + (t << 6);
        float h = hrow[c];
#pragma unroll
        for (int cc = 0; cc < CCOMP; ++cc) acc[cc] += h * w2[c * CCOMP + cc];
    }
#pragma unroll
    for (int cc = 0; cc < CCOMP; ++cc)
#pragma unroll
        for (int off = 32; off >= 1; off >>= 1) acc[cc] += __shfl_down(acc[cc], off);
    if (lane == 0) {
        float l[CCOMP];
        float mx = -1e30f;
#pragma unroll
        for (int cc = 0; cc < CCOMP; ++cc) { l[cc] = acc[cc] + b2[cc]; mx = fmaxf(mx, l[cc]); }
        float se = 0.f;
#pragma unroll
        for (int cc = 0; cc < CCOMP; ++cc) se += __expf(l[cc] - mx);
        float lse = __logf(se) + mx;
        red[wave] = lse - l[gold[row]];
#pragma unroll
        for (int cc = 0; cc < CCOMP; ++cc) out[row * CCOMP + cc] = l[cc];
    }
    __syncthreads();
    if (threadIdx.x == 0) partial[blockIdx.x] = red[0] + red[1] + red[2] + red[3];
}

// ---------------- rel head ----------------
__global__ __launch_bounds__(256) void rel_head_kernel(
    const float* __restrict__ Z, const float* __restrict__ b1,
    const float* __restrict__ w2, const float* __restrict__ b2,
    const int* __restrict__ gold, float* __restrict__ out,
    float* __restrict__ partial) {
    __shared__ float red[4];
    int wave = threadIdx.x >> 6, lane = threadIdx.x & 63;
    int row = blockIdx.x * 4 + wave;
    int b = row / PP;
    int p = row - b * PP;
    int i = p / 15;
    int jj = p - i * 15;
    int j = jj + (jj >= i ? 1 : 0);
    const float* z1 = Z + ((size_t)(b * 16 + i)) * 1024;
    const float* z2 = Z + ((size_t)(b * 16 + j)) * 1024 + 512;
    float a0 = 0.f, a1 = 0.f, a2 = 0.f;
#pragma unroll
    for (int t = 0; t < 8; ++t) {
        int c = lane + (t << 6);
        float h = tanhf(z1[c] + z2[c] + b1[c]);
        a0 += h * w2[c * 3 + 0];
        a1 += h * w2[c * 3 + 1];
        a2 += h * w2[c * 3 + 2];
    }
#pragma unroll
    for (int off = 32; off >= 1; off >>= 1) {
        a0 += __shfl_down(a0, off);
        a1 += __shfl_down(a1, off);
        a2 += __shfl_down(a2, off);
    }
    if (lane == 0) {
        float l0 = a0 + b2[0];
        float l1 = a1 + b2[1];
        float l2 = a2 + b2[2];
        float mx = fmaxf(l0, fmaxf(l1, l2));
        float se = __expf(l0 - mx) + __expf(l1 - mx) + __expf(l2 - mx);
        float lse = __logf(se) + mx;
        int g = gold[row];
        float lg = (g == 0) ? l0 : ((g == 1) ? l1 : l2);
        red[wave] = lse - lg;
        out[row * 3 + 0] = l0;
        out[row * 3 + 1] = l1;
        out[row * 3 + 2] = l2;
    }
    __syncthreads();
    if (threadIdx.x == 0) partial[blockIdx.x] = red[0] + red[1] + red[2] + red[3];
}

// ---------------- final loss reduction ----------------
__global__ __launch_bounds__(256) void finalize_kernel(
    const float* __restrict__ comp_p, const float* __restrict__ rel_p,
    float* __restrict__ out) {
    __shared__ float rc[4], rr[4];
    int tid = threadIdx.x;
    int wave = tid >> 6, lane = tid & 63;
    float sc = comp_p[tid];
    float sr = 0.f;
#pragma unroll
    for (int k = 0; k < 15; ++k) sr += rel_p[tid + k * 256];
#pragma unroll
    for (int off = 32; off >= 1; off >>= 1) {
        sc += __shfl_down(sc, off);
        sr += __shfl_down(sr, off);
    }
    if (lane == 0) { rc[wave] = sc; rr[wave] = sr; }
    __syncthreads();
    if (tid == 0) {
        out[51200] = (rc[0] + rc[1] + rc[2] + rc[3]) * (1.0f / 1024.0f);
        out[51201] = (rr[0] + rr[1] + rr[2] + rr[3]) * (1.0f / 15360.0f);
    }
}

extern "C" void kernel_launch(void* const* d_in, const int* in_sizes, int n_in,
                              void* d_out, int out_size, void* d_ws, size_t ws_size,
                              hipStream_t stream) {
    const float* lhs     = (const float*)d_in[0];
    const int* starts    = (const int*)d_in[1];
    const int* lens      = (const int*)d_in[2];
    const int* comps     = (const int*)d_in[3];
    const int* rels      = (const int*)d_in[4];
    const float* comp_w1 = (const float*)d_in[5];
    const float* comp_b1 = (const float*)d_in[6];
    const float* comp_w2 = (const float*)d_in[7];
    const float* comp_b2 = (const float*)d_in[8];
    const float* wq      = (const float*)d_in[9];
    const float* wk      = (const float*)d_in[10];
    const float* wv      = (const float*)d_in[11];
    const float* ln_g    = (const float*)d_in[12];
    const float* ln_b    = (const float*)d_in[13];
    const float* rel_w1  = (const float*)d_in[14];
    const float* rel_b1  = (const float*)d_in[15];
    const float* rel_w2  = (const float*)d_in[16];
    const float* rel_b2  = (const float*)d_in[17];
    float* out = (float*)d_out;
    float* ws = (float*)d_ws;

    float* pooled = ws;                       // 1024*768
    float* y2     = pooled + 786432;          // 1024*2816
    float* x      = y2 + 2883584;             // 1024*768
    float* Z      = x + 786432;               // 1024*1024
    float* comp_p = Z + 1048576;              // 256
    float* rel_p  = comp_p + 256;             // 3840
    u16* pooled_bf = (u16*)(rel_p + 3840);    // 786432 u16
    u16* x_bf      = pooled_bf + 786432;      // 786432
    u16* wcat_t    = x_bf + 786432;           // 2816*768
    u16* relw_t    = wcat_t + 2162688;        // 1024*768

    prep_kernel<<<2880, 256, 0, stream>>>(comp_w1, wq, wk, wv, rel_w1, wcat_t, relw_t);
    pool_kernel<<<1024, 256, 0, stream>>>(lhs, starts, lens, pooled, pooled_bf);
    gemm_pw_kernel<<<dim3(44, 16), 256, 0, stream>>>(pooled_bf, wcat_t, comp_b1, y2);
    attn_ln_kernel<<<64, 256, 0, stream>>>(y2, pooled, ln_g, ln_b, x, x_bf);
    gemm_z_kernel<<<dim3(16, 16), 256, 0, stream>>>(x_bf, relw_t, Z);
    comp_head_kernel<<<256, 256, 0, stream>>>(y2, comp_w2, comp_b2, comps, out, comp_p);
    rel_head_kernel<<<3840, 256, 0, stream>>>(Z, rel_b1, rel_w2, rel_b2, rels, out + 5120, rel_p);
    finalize_kernel<<<1, 256, 0, stream>>>(comp_p, rel_p, out);
}

// Round 6
// 243.237 us; speedup vs baseline: 2.2170x; 1.0369x over previous
//
#include <hip/hip_runtime.h>

#define BB 64
#define SS 512
#define HH 768
#define NSPAN 16
#define PP 240
#define CCOMP 5
#define CREL 3

typedef unsigned short u16;
typedef __attribute__((ext_vector_type(8))) short bf16x8;   // 8 bf16 in 4 VGPRs
typedef __attribute__((ext_vector_type(4))) float f32x4;

__device__ __forceinline__ u16 f2bf(float f) {
    union { float f; unsigned int i; } v; v.f = f;
    unsigned int x = v.i;
    unsigned int lsb = (x >> 16) & 1u;
    x += 0x7fffu + lsb;
    return (u16)(x >> 16);
}

// fast tanh: clamped exp-based (v_exp_f32), ~1e-6 abs err, no branches
__device__ __forceinline__ float ftanh(float x) {
    float xc = fminf(fmaxf(x, -15.f), 15.f);
    float e = __expf(2.f * xc);
    return (e - 1.f) / (e + 1.f);
}

// ---------------- weight prep: bf16 + transpose to [n][k] (K=768 contiguous) ----------------
__global__ __launch_bounds__(256) void prep_kernel(
    const float* __restrict__ cw1, const float* __restrict__ wq,
    const float* __restrict__ wk, const float* __restrict__ wv,
    const float* __restrict__ rw1, u16* __restrict__ wcat_t, u16* __restrict__ relw_t) {
    int blk = blockIdx.x;
    const float* W; int ldw, nt; u16* outp;
    if (blk < 384)        {             W = cw1; ldw = 512; nt = 16; outp = wcat_t; }
    else if (blk < 960)   { blk -= 384; W = wq;  ldw = 768; nt = 24; outp = wcat_t + (size_t)512 * 768; }
    else if (blk < 1536)  { blk -= 960; W = wk;  ldw = 768; nt = 24; outp = wcat_t + (size_t)1280 * 768; }
    else if (blk < 2112)  { blk -= 1536; W = wv; ldw = 768; nt = 24; outp = wcat_t + (size_t)2048 * 768; }
    else if (blk < 2496)  { blk -= 2112; W = rw1; ldw = 512; nt = 16; outp = relw_t; }
    else                  { blk -= 2496; W = rw1 + (size_t)768 * 512; ldw = 512; nt = 16; outp = relw_t + (size_t)512 * 768; }
    int tk = blk / nt, tn = blk % nt;
    int k0 = tk * 32, n0 = tn * 32;
    __shared__ u16 Ls[32][36];
    int tid = threadIdx.x;
    int tx = tid & 31, ty = tid >> 5;
#pragma unroll
    for (int r = 0; r < 4; ++r) {
        int k = ty + r * 8;
        Ls[tx][k] = f2bf(W[(size_t)(k0 + k) * ldw + n0 + tx]);
    }
    __syncthreads();
#pragma unroll
    for (int r = 0; r < 4; ++r) {
        int n = ty + r * 8;
        outp[(size_t)(n0 + n) * 768 + k0 + tx] = Ls[n][tx];
    }
}

// ---------------- span mean pooling (fp32 + bf16 outputs) ----------------
__global__ __launch_bounds__(256) void pool_kernel(
    const float* __restrict__ lhs, const int* __restrict__ starts,
    const int* __restrict__ lens, float* __restrict__ pooled, u16* __restrict__ pooled_bf) {
    int bn = blockIdx.x;
    int b = bn >> 4;
    int st = starts[bn];
    int ln = lens[bn];
    int tid = threadIdx.x;
    const float* base = lhs + ((size_t)b * SS + st) * HH;
    float a0 = 0.f, a1 = 0.f, a2 = 0.f;
    for (int s = 0; s <= ln; ++s) {
        const float* row = base + (size_t)s * HH;
        a0 += row[tid];
        a1 += row[tid + 256];
        a2 += row[tid + 512];
    }
    float inv = 1.0f / (float)(ln + 1);
    a0 *= inv; a1 *= inv; a2 *= inv;
    float* out = pooled + (size_t)bn * HH;
    u16* outb = pooled_bf + (size_t)bn * HH;
    out[tid] = a0;       out[tid + 256] = a1;       out[tid + 512] = a2;
    outb[tid] = f2bf(a0); outb[tid + 256] = f2bf(a1); outb[tid + 512] = f2bf(a2);
}

// ---------------- MFMA bf16 GEMM 64x64 tile, reg-prefetch pipeline ----------------
// y2[1024][2816] = [tanh(pooled@comp_w1+b1) | q | k | v]
__global__ __launch_bounds__(256) void gemm_pw_kernel(
    const u16* __restrict__ pooled_bf, const u16* __restrict__ wcat_t,
    const float* __restrict__ comp_b1, float* __restrict__ y2) {
    __shared__ u16 As[64][72];
    __shared__ u16 Bs[64][72];
    int ccol0 = blockIdx.x * 64;
    int row0 = blockIdx.y * 64;
    int act = (ccol0 < 512);
    int tid = threadIdx.x;
    int lane = tid & 63, w = tid >> 6;
    int q = lane >> 4, l15 = lane & 15;
    int wm = (w & 1) * 32, wn = (w >> 1) * 32;
    int r = tid >> 2, c0 = (tid & 3) * 16;
    const u16* ga = pooled_bf + (size_t)(row0 + r) * 768 + c0;
    const u16* gb = wcat_t + (size_t)(ccol0 + r) * 768 + c0;
    f32x4 acc[2][2];
#pragma unroll
    for (int i = 0; i < 2; ++i)
#pragma unroll
        for (int j = 0; j < 2; ++j) acc[i][j] = (f32x4){0.f, 0.f, 0.f, 0.f};

    uint4 va0 = *(const uint4*)(ga);
    uint4 va1 = *(const uint4*)(ga + 8);
    uint4 vb0 = *(const uint4*)(gb);
    uint4 vb1 = *(const uint4*)(gb + 8);
    for (int k0 = 0; k0 < 768; k0 += 64) {
        __syncthreads();
        *(uint4*)(&As[r][c0]) = va0;
        *(uint4*)(&As[r][c0 + 8]) = va1;
        *(uint4*)(&Bs[r][c0]) = vb0;
        *(uint4*)(&Bs[r][c0 + 8]) = vb1;
        __syncthreads();
        if (k0 + 64 < 768) {   // prefetch next tile while MFMAs run
            va0 = *(const uint4*)(ga + k0 + 64);
            va1 = *(const uint4*)(ga + k0 + 72);
            vb0 = *(const uint4*)(gb + k0 + 64);
            vb1 = *(const uint4*)(gb + k0 + 72);
        }
#pragma unroll
        for (int ks = 0; ks < 2; ++ks) {
            bf16x8 a0 = *(const bf16x8*)(&As[wm + l15][ks * 32 + q * 8]);
            bf16x8 a1 = *(const bf16x8*)(&As[wm + 16 + l15][ks * 32 + q * 8]);
            bf16x8 b0 = *(const bf16x8*)(&Bs[wn + l15][ks * 32 + q * 8]);
            bf16x8 b1 = *(const bf16x8*)(&Bs[wn + 16 + l15][ks * 32 + q * 8]);
            acc[0][0] = __builtin_amdgcn_mfma_f32_16x16x32_bf16(a0, b0, acc[0][0], 0, 0, 0);
            acc[0][1] = __builtin_amdgcn_mfma_f32_16x16x32_bf16(a0, b1, acc[0][1], 0, 0, 0);
            acc[1][0] = __builtin_amdgcn_mfma_f32_16x16x32_bf16(a1, b0, acc[1][0], 0, 0, 0);
            acc[1][1] = __builtin_amdgcn_mfma_f32_16x16x32_bf16(a1, b1, acc[1][1], 0, 0, 0);
        }
    }
    // C/D layout: col=lane&15, row=(lane>>4)*4+reg  [m89-verified]
#pragma unroll
    for (int tm = 0; tm < 2; ++tm)
#pragma unroll
        for (int tn = 0; tn < 2; ++tn)
#pragma unroll
            for (int reg = 0; reg < 4; ++reg) {
                int rr = row0 + wm + tm * 16 + q * 4 + reg;
                int cc = ccol0 + wn + tn * 16 + l15;
                float v = acc[tm][tn][reg];
                if (act) v = ftanh(v + comp_b1[cc]);
                y2[(size_t)rr * 2816 + cc] = v;
            }
}

// ---------------- MFMA bf16 GEMM 32x64 tile (512 blocks), reg-prefetch ----------------
// Z[1024][1024] = x @ [W_top | W_bot]
__global__ __launch_bounds__(256) void gemm_z_kernel(
    const u16* __restrict__ x_bf, const u16* __restrict__ relw_t, float* __restrict__ Z) {
    __shared__ u16 As[32][72];
    __shared__ u16 Bs[64][72];
    int ccol0 = blockIdx.x * 64;
    int row0 = blockIdx.y * 32;
    int tid = threadIdx.x;
    int lane = tid & 63, w = tid >> 6;
    int q = lane >> 4, l15 = lane & 15;
    int wm = (w & 1) * 16, wn = (w >> 1) * 32;
    int ra = tid >> 3, ca = (tid & 7) * 8;    // A: 32x64, 1 uint4/thread
    int rb = tid >> 2, cb = (tid & 3) * 16;   // B: 64x64, 2 uint4/thread
    const u16* ga = x_bf + (size_t)(row0 + ra) * 768 + ca;
    const u16* gb = relw_t + (size_t)(ccol0 + rb) * 768 + cb;
    f32x4 acc[2];
    acc[0] = (f32x4){0.f, 0.f, 0.f, 0.f};
    acc[1] = (f32x4){0.f, 0.f, 0.f, 0.f};

    uint4 va = *(const uint4*)(ga);
    uint4 vb0 = *(const uint4*)(gb);
    uint4 vb1 = *(const uint4*)(gb + 8);
    for (int k0 = 0; k0 < 768; k0 += 64) {
        __syncthreads();
        *(uint4*)(&As[ra][ca]) = va;
        *(uint4*)(&Bs[rb][cb]) = vb0;
        *(uint4*)(&Bs[rb][cb + 8]) = vb1;
        __syncthreads();
        if (k0 + 64 < 768) {
            va = *(const uint4*)(ga + k0 + 64);
            vb0 = *(const uint4*)(gb + k0 + 64);
            vb1 = *(const uint4*)(gb + k0 + 72);
        }
#pragma unroll
        for (int ks = 0; ks < 2; ++ks) {
            bf16x8 a0 = *(const bf16x8*)(&As[wm + l15][ks * 32 + q * 8]);
            bf16x8 b0 = *(const bf16x8*)(&Bs[wn + l15][ks * 32 + q * 8]);
            bf16x8 b1 = *(const bf16x8*)(&Bs[wn + 16 + l15][ks * 32 + q * 8]);
            acc[0] = __builtin_amdgcn_mfma_f32_16x16x32_bf16(a0, b0, acc[0], 0, 0, 0);
            acc[1] = __builtin_amdgcn_mfma_f32_16x16x32_bf16(a0, b1, acc[1], 0, 0, 0);
        }
    }
#pragma unroll
    for (int tn = 0; tn < 2; ++tn)
#pragma unroll
        for (int reg = 0; reg < 4; ++reg) {
            int rr = row0 + wm + q * 4 + reg;
            int cc = ccol0 + wn + tn * 16 + l15;
            Z[(size_t)rr * 1024 + cc] = acc[tn][reg];
        }
}

// ---------------- 16x16 attention + residual + LayerNorm (bf16 out only) ----------------
__global__ __launch_bounds__(256) void attn_ln_kernel(
    const float* __restrict__ y2, const float* __restrict__ pooled,
    const float* __restrict__ ln_g, const float* __restrict__ ln_b,
    u16* __restrict__ x_bf) {
    __shared__ float ks[16][772];
    __shared__ float Ssm[16][17];
    int b = blockIdx.x;
    int tid = threadIdx.x;
    int n = tid >> 4;
    int hl = tid & 15;

    for (int u = 0; u < 48; ++u) {
        int h = hl + (u << 4);
        ks[n][h] = y2[((size_t)(b * 16 + n)) * 2816 + 1280 + h];
    }
    __syncthreads();

    int m = tid & 15;
    const float* qrow = y2 + ((size_t)(b * 16 + n)) * 2816 + 512;
    float dot = 0.f;
    for (int h = 0; h < 768; h += 4) {
        float4 qv = *(const float4*)(qrow + h);
        float4 kv = *(const float4*)(&ks[m][h]);
        dot += qv.x * kv.x + qv.y * kv.y + qv.z * kv.z + qv.w * kv.w;
    }
    float sval = dot * 0.03608439182435161f;  // 1/sqrt(768)
    float mx = sval;
#pragma unroll
    for (int off = 8; off >= 1; off >>= 1) mx = fmaxf(mx, __shfl_xor(mx, off, 16));
    float pexp = __expf(sval - mx);
    float psum = pexp;
#pragma unroll
    for (int off = 8; off >= 1; off >>= 1) psum += __shfl_xor(psum, off, 16);
    Ssm[n][m] = pexp / psum;
    __syncthreads();

    for (int u = 0; u < 48; ++u) {
        int h = hl + (u << 4);
        ks[n][h] = y2[((size_t)(b * 16 + n)) * 2816 + 2048 + h];
    }
    __syncthreads();

    float sc[16];
#pragma unroll
    for (int mm = 0; mm < 16; ++mm) sc[mm] = Ssm[n][mm];
    int row = b * 16 + n;
    const float* prow = pooled + (size_t)row * HH;
    float xv[48];
    float ssum = 0.f, ssq = 0.f;
    for (int u = 0; u < 48; ++u) {
        int h = hl + (u << 4);
        float a = 0.f;
#pragma unroll
        for (int mm = 0; mm < 16; ++mm) a += sc[mm] * ks[mm][h];
        float v = prow[h] + a;
        xv[u] = v;
        ssum += v;
        ssq += v * v;
    }
#pragma unroll
    for (int off = 8; off >= 1; off >>= 1) {
        ssum += __shfl_xor(ssum, off, 16);
        ssq += __shfl_xor(ssq, off, 16);
    }
    float mu = ssum * (1.0f / 768.0f);
    float var = ssq * (1.0f / 768.0f) - mu * mu;
    float rs = rsqrtf(var + 1e-5f);
    u16* xrow_bf = x_bf + (size_t)row * HH;
    for (int u = 0; u < 48; ++u) {
        int h = hl + (u << 4);
        xrow_bf[h] = f2bf((xv[u] - mu) * rs * ln_g[h] + ln_b[h]);
    }
}

// ---------------- merged heads: blocks [0,3840) = rel, [3840,4096) = comp ----------------
__global__ __launch_bounds__(256) void heads_kernel(
    const float* __restrict__ Z, const float* __restrict__ rb1,
    const float* __restrict__ rw2, const float* __restrict__ rb2,
    const int* __restrict__ rels,
    const float* __restrict__ y2, const float* __restrict__ cw2,
    const float* __restrict__ cb2, const int* __restrict__ comps,
    float* __restrict__ out, float* __restrict__ rel_p, float* __restrict__ comp_p) {
    __shared__ float red[4];
    int wave = threadIdx.x >> 6, lane = threadIdx.x & 63;
    if (blockIdx.x < 3840) {
        int row = blockIdx.x * 4 + wave;   // 0..15359
        int b = row / PP;
        int p = row - b * PP;
        int i = p / 15;
        int jj = p - i * 15;
        int j = jj + (jj >= i ? 1 : 0);
        const float* z1 = Z + ((size_t)(b * 16 + i)) * 1024;
        const float* z2 = Z + ((size_t)(b * 16 + j)) * 1024 + 512;
        float a0 = 0.f, a1 = 0.f, a2 = 0.f;
#pragma unroll
        for (int t = 0; t < 8; ++t) {
            int c = lane + (t << 6);
            float h = ftanh(z1[c] + z2[c] + rb1[c]);
            a0 += h * rw2[c * 3 + 0];
            a1 += h * rw2[c * 3 + 1];
            a2 += h * rw2[c * 3 + 2];
        }
#pragma unroll
        for (int off = 32; off >= 1; off >>= 1) {
            a0 += __shfl_down(a0, off);
            a1 += __shfl_down(a1, off);
            a2 += __shfl_down(a2, off);
        }
        if (lane == 0) {
            float l0 = a0 + rb2[0];
            float l1 = a1 + rb2[1];
            float l2 = a2 + rb2[2];
            float mx = fmaxf(l0, fmaxf(l1, l2));
            float se = __expf(l0 - mx) + __expf(l1 - mx) + __expf(l2 - mx);
            float lse = __logf(se) + mx;
            int g = rels[row];
            float lg = (g == 0) ? l0 : ((g == 1) ? l1 : l2);
            red[wave] = lse - lg;
            float* o = out + 5120 + (size_t)row * 3;
            o[0] = l0; o[1] = l1; o[2] = l2;
        }
        __syncthreads();
        if (threadIdx.x == 0) rel_p[blockIdx.x] = red[0] + red[1] + red[2] + red[3];
    } else {
        int row = (blockIdx.x - 3840) * 4 + wave;  // 0..1023
        const float* hrow = y2 + (size_t)row * 2816;
        float acc[CCOMP] = {0.f, 0.f, 0.f, 0.f, 0.f};
#pragma unroll
        for (int t = 0; t < 8; ++t) {
            int c = lane + (t << 6);
            float h = hrow[c];
#pragma unroll
            for (int cc = 0; cc < CCOMP; ++cc) acc[cc] += h * cw2[c * CCOMP + cc];
        }
#pragma unroll
        for (int cc = 0; cc < CCOMP; ++cc)
#pragma unroll
            for (int off = 32; off >= 1; off >>= 1) acc[cc] += __shfl_down(acc[cc], off);
        if (lane == 0) {
            float l[CCOMP];
            float mx = -1e30f;
#pragma unroll
            for (int cc = 0; cc < CCOMP; ++cc) { l[cc] = acc[cc] + cb2[cc]; mx = fmaxf(mx, l[cc]); }
            float se = 0.f;
#pragma unroll
            for (int cc = 0; cc < CCOMP; ++cc) se += __expf(l[cc] - mx);
            float lse = __logf(se) + mx;
            red[wave] = lse - l[comps[row]];
#pragma unroll
            for (int cc = 0; cc < CCOMP; ++cc) out[row * CCOMP + cc] = l[cc];
        }
        __syncthreads();
        if (threadIdx.x == 0) comp_p[blockIdx.x - 3840] = red[0] + red[1] + red[2] + red[3];
    }
}

// ---------------- final loss reduction ----------------
__global__ __launch_bounds__(256) void finalize_kernel(
    const float* __restrict__ comp_p, const float* __restrict__ rel_p,
    float* __restrict__ out) {
    __shared__ float rc[4], rr[4];
    int tid = threadIdx.x;
    int wave = tid >> 6, lane = tid & 63;
    float sc = comp_p[tid];
    float sr = 0.f;
#pragma unroll
    for (int k = 0; k < 15; ++k) sr += rel_p[tid + k * 256];
#pragma unroll
    for (int off = 32; off >= 1; off >>= 1) {
        sc += __shfl_down(sc, off);
        sr += __shfl_down(sr, off);
    }
    if (lane == 0) { rc[wave] = sc; rr[wave] = sr; }
    __syncthreads();
    if (tid == 0) {
        out[51200] = (rc[0] + rc[1] + rc[2] + rc[3]) * (1.0f / 1024.0f);
        out[51201] = (rr[0] + rr[1] + rr[2] + rr[3]) * (1.0f / 15360.0f);
    }
}

extern "C" void kernel_launch(void* const* d_in, const int* in_sizes, int n_in,
                              void* d_out, int out_size, void* d_ws, size_t ws_size,
                              hipStream_t stream) {
    const float* lhs     = (const float*)d_in[0];
    const int* starts    = (const int*)d_in[1];
    const int* lens      = (const int*)d_in[2];
    const int* comps     = (const int*)d_in[3];
    const int* rels      = (const int*)d_in[4];
    const float* comp_w1 = (const float*)d_in[5];
    const float* comp_b1 = (const float*)d_in[6];
    const float* comp_w2 = (const float*)d_in[7];
    const float* comp_b2 = (const float*)d_in[8];
    const float* wq      = (const float*)d_in[9];
    const float* wk      = (const float*)d_in[10];
    const float* wv      = (const float*)d_in[11];
    const float* ln_g    = (const float*)d_in[12];
    const float* ln_b    = (const float*)d_in[13];
    const float* rel_w1  = (const float*)d_in[14];
    const float* rel_b1  = (const float*)d_in[15];
    const float* rel_w2  = (const float*)d_in[16];
    const float* rel_b2  = (const float*)d_in[17];
    float* out = (float*)d_out;
    float* ws = (float*)d_ws;

    float* pooled = ws;                       // 1024*768
    float* y2     = pooled + 786432;          // 1024*2816
    float* Z      = y2 + 2883584;             // 1024*1024
    float* comp_p = Z + 1048576;              // 256
    float* rel_p  = comp_p + 256;             // 3840
    u16* pooled_bf = (u16*)(rel_p + 3840);    // 786432 u16
    u16* x_bf      = pooled_bf + 786432;      // 786432
    u16* wcat_t    = x_bf + 786432;           // 2816*768
    u16* relw_t    = wcat_t + 2162688;        // 1024*768

    prep_kernel<<<2880, 256, 0, stream>>>(comp_w1, wq, wk, wv, rel_w1, wcat_t, relw_t);
    pool_kernel<<<1024, 256, 0, stream>>>(lhs, starts, lens, pooled, pooled_bf);
    gemm_pw_kernel<<<dim3(44, 16), 256, 0, stream>>>(pooled_bf, wcat_t, comp_b1, y2);
    attn_ln_kernel<<<64, 256, 0, stream>>>(y2, pooled, ln_g, ln_b, x_bf);
    gemm_z_kernel<<<dim3(16, 32), 256, 0, stream>>>(x_bf, relw_t, Z);
    heads_kernel<<<4096, 256, 0, stream>>>(Z, rel_b1, rel_w2, rel_b2, rels,
                                           y2, comp_w2, comp_b2, comps,
                                           out, rel_p, comp_p);
    finalize_kernel<<<1, 256, 0, stream>>>(comp_p, rel_p, out);
}